// Round 9
// baseline (1138.015 us; speedup 1.0000x reference)
//
#include <hip/hip_runtime.h>
#include <hip/hip_bf16.h>

#define N_NODES 100000
#define N_EDGES 1600000
#define F_IN    256
#define F_OUT   64
#define N_REL   2
#define N_BASES 30
#define N_NT    12          // 192 output cols / 16
#define N_KS    8           // 256 k / 32
#define NB      ((N_NODES + 127) / 128)               // 782 dst-buckets
#define NCELL   (NB * 8)                              // 6256 (bucket, sub) cells

typedef __attribute__((ext_vector_type(8))) short bf16x8;
typedef __attribute__((ext_vector_type(4))) float f32x4;

__device__ inline unsigned short f2bf(float f) {            // RTNE
    unsigned u = __float_as_uint(f);
    unsigned r = u + 0x7FFF + ((u >> 16) & 1);
    return (unsigned short)(r >> 16);
}
__device__ inline float bf2f(unsigned short b) {
    return __uint_as_float(((unsigned)b) << 16);
}

// ---------------------------------------------------------------------------
// Kernel 0: build B-operand fragments of W = [att@basis | att@basis | root]
// in bf16 hi/lo split, laid out so gemm lane loads one dwordx4 per frag.
// ---------------------------------------------------------------------------
__global__ __launch_bounds__(256) void wcomp_kernel(
    const float* __restrict__ att, const float* __restrict__ basis,
    const float* __restrict__ root,
    unsigned short* __restrict__ wb_hi, unsigned short* __restrict__ wb_lo)
{
    int idx = blockIdx.x * 256 + threadIdx.x;
    if (idx >= N_KS * N_NT * 64) return;
    const int lane  = idx & 63;
    const int nt    = (idx >> 6) % N_NT;
    const int ks    = idx / (N_NT * 64);
    const int c     = nt * 16 + (lane & 15);      // 0..191
    const int kbase = ks * 32 + (lane >> 4) * 8;
    const int m     = c >> 6;                     // 0,1 rel ; 2 root
    const int f     = c & 63;

    bf16x8 hi, lo;
    #pragma unroll
    for (int i = 0; i < 8; ++i) {
        int k = kbase + i;
        float v;
        if (m == 2) {
            v = root[k * F_OUT + f];
        } else {
            v = 0.f;
            #pragma unroll
            for (int b = 0; b < N_BASES; ++b)
                v += att[m * N_BASES + b] * basis[((long)b * F_IN + k) * F_OUT + f];
        }
        unsigned short h = f2bf(v);
        unsigned short l = f2bf(v - bf2f(h));
        hi[i] = (short)h;
        lo[i] = (short)l;
    }
    *reinterpret_cast<bf16x8*>(wb_hi + (long)idx * 8) = hi;
    *reinterpret_cast<bf16x8*>(wb_lo + (long)idx * 8) = lo;
}

// ---------------------------------------------------------------------------
// Kernel 1: MFMA GEMM [100000,256]x[256,192], bf16 2-term split (hi/lo),
// C = Ahi*Bhi + Alo*Bhi + Ahi*Blo accumulated in fp32. Barrier-free.
//   cols 0..127  -> h[rel][n][f], cols 128..191 -> out = x@root + bias
// ---------------------------------------------------------------------------
__global__ __launch_bounds__(256) void gemm_kernel(
    const float* __restrict__ x,
    const unsigned short* __restrict__ wb_hi,
    const unsigned short* __restrict__ wb_lo,
    const float* __restrict__ bias,
    float* __restrict__ h, float* __restrict__ out)
{
    const int lane = threadIdx.x & 63;
    const int wv   = threadIdx.x >> 6;
    const long row0 = (long)blockIdx.x * 128 + wv * 32;
    if (row0 >= N_NODES) return;          // 100000 % 32 == 0: all-or-nothing

    const int mrow = lane & 15;           // A row within 16-tile
    const int kgrp = lane >> 4;           // 0..3, k-subgroup of 8

    f32x4 acc[2][N_NT];
    #pragma unroll
    for (int mt = 0; mt < 2; ++mt)
        #pragma unroll
        for (int nt = 0; nt < N_NT; ++nt)
            acc[mt][nt] = (f32x4){0.f, 0.f, 0.f, 0.f};

    const float* xp = x + (row0 + mrow) * F_IN + kgrp * 8;

    for (int ks = 0; ks < N_KS; ++ks) {
        // ---- A fragments: 8 consecutive fp32 per lane -> bf16 hi/lo
        bf16x8 ah[2], al[2];
        #pragma unroll
        for (int mt = 0; mt < 2; ++mt) {
            const float* p = xp + (long)mt * 16 * F_IN + ks * 32;
            float4 f0 = *reinterpret_cast<const float4*>(p);
            float4 f1 = *reinterpret_cast<const float4*>(p + 4);
            float fv[8] = {f0.x, f0.y, f0.z, f0.w, f1.x, f1.y, f1.z, f1.w};
            #pragma unroll
            for (int i = 0; i < 8; ++i) {
                unsigned short hb = f2bf(fv[i]);
                ah[mt][i] = (short)hb;
                al[mt][i] = (short)f2bf(fv[i] - bf2f(hb));
            }
        }
        // ---- B fragments + MFMA
        const unsigned short* bh_base = wb_hi + ((long)(ks * N_NT) * 64 + lane) * 8;
        const unsigned short* bl_base = wb_lo + ((long)(ks * N_NT) * 64 + lane) * 8;
        #pragma unroll
        for (int nt = 0; nt < N_NT; ++nt) {
            bf16x8 bh = *reinterpret_cast<const bf16x8*>(bh_base + (long)nt * 64 * 8);
            bf16x8 bl = *reinterpret_cast<const bf16x8*>(bl_base + (long)nt * 64 * 8);
            #pragma unroll
            for (int mt = 0; mt < 2; ++mt) {
                acc[mt][nt] = __builtin_amdgcn_mfma_f32_16x16x32_bf16(ah[mt], bh, acc[mt][nt], 0, 0, 0);
                acc[mt][nt] = __builtin_amdgcn_mfma_f32_16x16x32_bf16(al[mt], bh, acc[mt][nt], 0, 0, 0);
                acc[mt][nt] = __builtin_amdgcn_mfma_f32_16x16x32_bf16(ah[mt], bl, acc[mt][nt], 0, 0, 0);
            }
        }
    }

    // ---- epilogue: D lane mapping col=lane&15, row=(lane>>4)*4+i
    const int ccol = lane & 15;
    const int rsub = (lane >> 4) * 4;
    #pragma unroll
    for (int mt = 0; mt < 2; ++mt) {
        #pragma unroll
        for (int nt = 0; nt < N_NT; ++nt) {
            const int rel = nt >> 2;                    // 0,1 -> h ; 2 -> out
            const int fc  = (nt & 3) * 16 + ccol;
            float badd = (rel == 2) ? bias[fc] : 0.f;
            #pragma unroll
            for (int i = 0; i < 4; ++i) {
                long row = row0 + mt * 16 + rsub + i;
                float v = acc[mt][nt][i] + badd;
                if (rel == 2) out[row * F_OUT + fc] = v;
                else          h[((long)rel * N_NODES + row) * F_OUT + fc] = v;
            }
        }
    }
}

// ---------------------------------------------------------------------------
// Kernel 2: per-node counts (mean denominator) + per-(bucket,sub) counts.
// sub = blockIdx.x & 7 — pure function of edge index, reused by binscatter.
// ---------------------------------------------------------------------------
__global__ __launch_bounds__(256) void hist2_kernel(
    const int* __restrict__ edge_index, int* __restrict__ hist,
    int* __restrict__ h2)
{
    int e = blockIdx.x * 256 + threadIdx.x;
    if (e >= N_EDGES) return;
    int dst = edge_index[N_EDGES + e];
    atomicAdd(&hist[dst], 1);
    atomicAdd(&h2[(dst >> 7) * 8 + (blockIdx.x & 7)], 1);
}

// ---------------------------------------------------------------------------
// Kernel 3: exclusive scan over the 6256 (bucket,sub) cells. Single block.
// sub_base[NCELL] = N_EDGES sentinel.
// ---------------------------------------------------------------------------
__global__ __launch_bounds__(1024) void bscan_kernel(
    const int* __restrict__ h2, int* __restrict__ sub_base)
{
    __shared__ int s[1024];
    __shared__ int carry;
    const int t = threadIdx.x;
    if (t == 0) carry = 0;
    __syncthreads();
    for (int base = 0; base < NCELL; base += 1024) {
        int i = base + t;
        int v = (i < NCELL) ? h2[i] : 0;
        s[t] = v;
        __syncthreads();
        #pragma unroll
        for (int off = 1; off < 1024; off <<= 1) {
            int y = (t >= off) ? s[t - off] : 0;
            __syncthreads();
            s[t] += y;
            __syncthreads();
        }
        int c = carry;
        __syncthreads();                       // all threads have read carry
        if (i < NCELL) sub_base[i] = c + s[t] - v;   // exclusive
        if (t == 1023) carry = c + s[1023];
        __syncthreads();
    }
    if (t == 0) sub_base[NCELL] = carry;       // == N_EDGES
}

// ---------------------------------------------------------------------------
// Kernel 4: binned scatter into XCD-private sub-frontiers.
// Blocks with blockIdx&7==s write only cell (b,s) regions; with round-robin
// block->XCD dispatch each 64B frontier line is dirtied by one XCD only.
// payload: src (17b) | et<<17 | (dst&127)<<18
// ---------------------------------------------------------------------------
__global__ __launch_bounds__(256) void binscatter_kernel(
    const int* __restrict__ edge_index, const int* __restrict__ edge_type,
    const int* __restrict__ sub_base, int* __restrict__ cur2,
    int* __restrict__ belist)
{
    int e = blockIdx.x * 256 + threadIdx.x;
    if (e >= N_EDGES) return;
    int src = edge_index[e];
    int dst = edge_index[N_EDGES + e];
    int et  = edge_type[e];
    int cell = (dst >> 7) * 8 + (blockIdx.x & 7);
    int pos = sub_base[cell] + atomicAdd(&cur2[cell * 16], 1);   // 64B-padded ctr
    belist[pos] = src | (et << 17) | ((dst & 127) << 18);
}

// ---------------------------------------------------------------------------
// Kernel 5: bucket gather. One block per bucket: accumulate all its edges'
// h-rows into LDS acc[128][64] (ds_add_f32, conflict-free), then
// out[node] += acc/max(cnt,1).  Replaces sortlocal+gather; no elist.
// ---------------------------------------------------------------------------
__global__ __launch_bounds__(512) void bucketgather_kernel(
    const int* __restrict__ sub_base, const int* __restrict__ belist,
    const int* __restrict__ hist, const float* __restrict__ h,
    float* __restrict__ out)
{
    __shared__ float acc[128][64];     // 32 KB
    const int t    = threadIdx.x;
    const int lane = t & 63;
    const int wv   = t >> 6;           // 0..7
    const int b    = blockIdx.x;

    float* af = &acc[0][0];
    #pragma unroll
    for (int i = t; i < 128 * 64; i += 512) af[i] = 0.f;
    __syncthreads();

    const int beg = sub_base[b * 8];
    const int end = sub_base[b * 8 + 8];
    for (int i = beg + wv; i < end; i += 8) {
        int v   = belist[i];
        int src = v & 0x1FFFF;
        int et  = (v >> 17) & 1;
        int dlo = (v >> 18) & 127;
        float val = h[((long)et * N_NODES + src) * F_OUT + lane];
        atomicAdd(&acc[dlo][lane], val);
    }
    __syncthreads();

    const int node0 = b << 7;
    for (int r = wv; r < 128; r += 8) {
        int node = node0 + r;
        if (node < N_NODES) {
            float inv = 1.0f / fmaxf((float)hist[node], 1.0f);
            out[(long)node * F_OUT + lane] += acc[r][lane] * inv;
        }
    }
}

// ---------------------------------------------------------------------------
extern "C" void kernel_launch(void* const* d_in, const int* in_sizes, int n_in,
                              void* d_out, int out_size, void* d_ws, size_t ws_size,
                              hipStream_t stream)
{
    const float* x          = (const float*)d_in[0];
    const int*   edge_index = (const int*)  d_in[1];
    const int*   edge_type  = (const int*)  d_in[2];
    const float* basis      = (const float*)d_in[3];
    const float* att        = (const float*)d_in[4];
    const float* root       = (const float*)d_in[5];
    const float* bias       = (const float*)d_in[6];
    float* out = (float*)d_out;

    char* ws = (char*)d_ws;
    size_t off = 0;
    unsigned short* wb_hi = (unsigned short*)(ws + off); off += (size_t)N_KS * N_NT * 64 * 8 * 2;
    unsigned short* wb_lo = (unsigned short*)(ws + off); off += (size_t)N_KS * N_NT * 64 * 8 * 2;
    float* h        = (float*)(ws + off); off += (size_t)N_REL * N_NODES * F_OUT * 4;
    // zero region start (hist, h2, cur2 contiguous)
    int*   hist     = (int*)  (ws + off); off += (size_t)N_NODES * 4;
    int*   h2       = (int*)  (ws + off); off += (size_t)NCELL * 4;
    int*   cur2     = (int*)  (ws + off); off += (size_t)NCELL * 16 * 4;  // 64B-padded
    // zero region end
    int*   sub_base = (int*)  (ws + off); off += (size_t)(NCELL + 1) * 4;
    int*   belist   = (int*)  (ws + off); off += (size_t)N_EDGES * 4;

    hipMemsetAsync(hist, 0, (size_t)(N_NODES + NCELL + NCELL * 16) * 4, stream);

    wcomp_kernel<<<(N_KS * N_NT * 64 + 255) / 256, 256, 0, stream>>>(
        att, basis, root, wb_hi, wb_lo);

    gemm_kernel<<<(N_NODES + 127) / 128, 256, 0, stream>>>(
        x, wb_hi, wb_lo, bias, h, out);

    hist2_kernel<<<(N_EDGES + 255) / 256, 256, 0, stream>>>(
        edge_index, hist, h2);

    bscan_kernel<<<1, 1024, 0, stream>>>(h2, sub_base);

    binscatter_kernel<<<(N_EDGES + 255) / 256, 256, 0, stream>>>(
        edge_index, edge_type, sub_base, cur2, belist);

    bucketgather_kernel<<<NB, 512, 0, stream>>>(
        sub_base, belist, hist, h, out);
}